// Round 19
// baseline (392.819 us; speedup 1.0000x reference)
//
#include <hip/hip_runtime.h>
#include <hip/hip_bf16.h>
#include <stdint.h>
#include <math.h>

#define T_SEQ 2048
#define D_MODEL 2048
#define KV_DIM 512
#define QKV_LD 3072  // fused q|k|v row stride
#define NHEADS 16
#define HDIM 128
#define BATCH 4
#define MT (BATCH * T_SEQ)  // 8192 rows

typedef __attribute__((ext_vector_type(4))) float f32x4;
typedef __attribute__((ext_vector_type(8))) __bf16 bf16x8;
typedef __attribute__((ext_vector_type(4))) __bf16 bf16x4;
typedef __attribute__((ext_vector_type(8))) unsigned short u16x8;
typedef __attribute__((ext_vector_type(4))) unsigned short u16x4;
typedef __attribute__((ext_vector_type(4))) short s16x4;

static __device__ __forceinline__ unsigned short f32_bf16(float f) {
  unsigned u = __float_as_uint(f);
  u += 0x7fff + ((u >> 16) & 1);  // RNE
  return (unsigned short)(u >> 16);
}

static __device__ __forceinline__ void gload_lds16(const void* g, void* l) {
  __builtin_amdgcn_global_load_lds(
      (__attribute__((address_space(1))) void*)(const_cast<void*>(g)),
      (__attribute__((address_space(3))) void*)l, 16, 0, 0);
}

static __device__ __forceinline__ f32x4 mfma16(bf16x8 a, bf16x8 b, f32x4 c) {
  return __builtin_amdgcn_mfma_f32_16x16x32_bf16(a, b, c, 0, 0, 0);
}

// K=16 bf16 MFMA: A/B = 4 bf16 (k = (lane>>4)*4+j), C/D layout same as 16x16x32.
static __device__ __forceinline__ f32x4 mfma16x16(u16x4 a, u16x4 b, f32x4 c) {
#if __has_builtin(__builtin_amdgcn_mfma_f32_16x16x16bf16_1k)
  return __builtin_amdgcn_mfma_f32_16x16x16bf16_1k(
      __builtin_bit_cast(s16x4, a), __builtin_bit_cast(s16x4, b), c, 0, 0, 0);
#elif __has_builtin(__builtin_amdgcn_mfma_f32_16x16x16_bf16)
  return __builtin_amdgcn_mfma_f32_16x16x16_bf16(
      __builtin_bit_cast(bf16x4, a), __builtin_bit_cast(bf16x4, b), c, 0, 0, 0);
#else
  f32x4 d;
  asm("v_mfma_f32_16x16x16_bf16 %0, %1, %2, %3" : "=v"(d) : "v"(a), "v"(b), "v"(c));
  return d;
#endif
}

static __device__ __forceinline__ void barx() {
  asm volatile("" ::: "memory");
  __builtin_amdgcn_s_barrier();
  asm volatile("" ::: "memory");
}

// swizzled [rows][8 units of 16B] u16-index helper (unit ^= row&7) — attn V layout
#define VIDX(d, c) (((((d) << 3) + ((c) ^ ((d) & 7))) << 3))

// ---------------- fused prep: x f32->bf16 + 4x weight transpose ----------------
// blocks [0, 16384): cvt of x (each block = 256 x f32x4)
// blocks [16384, 26624): 32x32 transpose tiles (Wq/Wk/Wv/Wo -> bf16 B^T panels)
#define CVT_BLOCKS 16384
__global__ void prep_kernel(const float* __restrict__ x, const float* __restrict__ Wq,
                            const float* __restrict__ Wk, const float* __restrict__ Wv,
                            const float* __restrict__ Wo, unsigned short* __restrict__ xb,
                            unsigned short* __restrict__ WqkvT,
                            unsigned short* __restrict__ WoT) {
  const int bid = blockIdx.x;
  const int tid = threadIdx.x;
  if (bid < CVT_BLOCKS) {
    const int i = bid * 256 + tid;
    f32x4 v = ((const f32x4*)x)[i];
    u16x4 o;
#pragma unroll
    for (int j = 0; j < 4; ++j) o[j] = f32_bf16(v[j]);
    ((u16x4*)xb)[i] = o;
    return;
  }
  const int tb = bid - CVT_BLOCKS;
  const float* W;
  unsigned short* Wt;
  int N, bx, by;
  if (tb < 4096) {
    W = Wq; Wt = WqkvT; N = 2048; bx = tb & 63; by = tb >> 6;
  } else if (tb < 5120) {
    const int r = tb - 4096;
    W = Wk; Wt = WqkvT + (size_t)2048 * 2048; N = 512; bx = r & 15; by = r >> 4;
  } else if (tb < 6144) {
    const int r = tb - 5120;
    W = Wv; Wt = WqkvT + (size_t)2560 * 2048; N = 512; bx = r & 15; by = r >> 4;
  } else {
    const int r = tb - 6144;
    W = Wo; Wt = WoT; N = 2048; bx = r & 63; by = r >> 6;
  }
  const int K = 2048;
  __shared__ float tile[32][33];
  const int x0 = bx * 32, y0 = by * 32;
  const int tx = tid & 31, ty = tid >> 5;
#pragma unroll
  for (int i = 0; i < 32; i += 8)
    tile[ty + i][tx] = W[(size_t)(y0 + ty + i) * N + x0 + tx];
  __syncthreads();
#pragma unroll
  for (int i = 0; i < 32; i += 8)
    Wt[(size_t)(x0 + ty + i) * K + y0 + tx] = f32_bf16(tile[tx][ty + i]);
}

// ---------------- 256xBN x64 8-phase GEMM: C[M,N] = A[M,K] @ Bt[N,K]^T ----------------
// NB=4 -> BN=256, LDS 128KB (proven best; NB=2 regressed — A-staging doubles, R17).
// LDS subtile = 16 rows x 32 u16 (1KB); 16B-unit swizzle phys = logical ^ ((row>>1)&3)
// on both staging source col and fragment read (rule #21 involution).
template <typename OutT, bool HAS_BIAS, int NB>
__global__ __launch_bounds__(512, 2) void gemm256_kernel(
    const unsigned short* __restrict__ A, const unsigned short* __restrict__ Bt,
    OutT* __restrict__ C, const float* __restrict__ bias, int M, int N, int K) {
  __shared__ unsigned short As[2][16384];
  __shared__ unsigned short Bs[2][4096 * NB];
  const int tid = threadIdx.x;
  const int wave = tid >> 6, lane = tid & 63;
  const int lr = lane & 15, lh = lane >> 4;
  const int wm = wave >> 2, wn = wave & 3;  // 2M x 4N waves

  // bijective XCD swizzle (nwg % 8 == 0 for our grids)
  const int gx = gridDim.x;
  const int nwg = gx * gridDim.y;
  int flat = blockIdx.y * gx + blockIdx.x;
  flat = (flat & 7) * (nwg >> 3) + (flat >> 3);
  const int bx = flat % gx, by = flat / gx;

  const unsigned short* Ag = A + (size_t)by * 256 * K;
  const unsigned short* Bg = Bt + (size_t)bx * (64 * NB) * K;

  // staging geometry: thread stages 16B unit (lane&3) of subtile row (lane>>2)
  const int srow_lo = lane >> 2;
  const int scol = ((lane & 3) ^ ((srow_lo >> 1) & 3)) * 8;  // inverse-swizzled source col (u16)

#define STAGE_HALF(SRC, DST, HK, NS)                                          \
  {                                                                           \
    _Pragma("unroll") for (int s = 0; s < (NS); ++s) {                        \
      const int jj = s * 8 + wave;                                            \
      gload_lds16((SRC) + (size_t)(jj * 16 + srow_lo) * K + (HK) * 32 + scol, \
                  (char*)(DST) + (jj * 2 + (HK)) * 1024);                     \
    }                                                                         \
  }
#define VMC_CHECK()                                                           \
  {                                                                           \
    if constexpr (NB == 4) asm volatile("s_waitcnt vmcnt(4)" ::: "memory");   \
    else asm volatile("s_waitcnt vmcnt(3)" ::: "memory");                     \
  }

  // fragment read offsets (u16): row lr, logical 16B-unit lh -> phys lh^((lr>>1)&3)
  const int aoff = lr * 32 + ((lh ^ ((lr >> 1) & 3)) * 8);
  const int abase = wm * 8 * 1024;
  const int bbase = wn * NB * 1024;

  f32x4 acc[8][NB] = {};
  bf16x8 af[4], bf[NB];

#define PH_READ_A(MH, KS)                                                   \
  {                                                                         \
    _Pragma("unroll") for (int m = 0; m < 4; ++m)                           \
      af[m] = *(const bf16x8*)&As[cur][abase + ((MH)*4 + m) * 1024 + (KS)*512 + aoff]; \
  }
#define PH_READ_B(KS)                                                       \
  {                                                                         \
    _Pragma("unroll") for (int n = 0; n < NB; ++n)                          \
      bf[n] = *(const bf16x8*)&Bs[cur][bbase + n * 1024 + (KS)*512 + aoff]; \
  }
#define PH_MFMA(MH)                                                         \
  {                                                                         \
    __builtin_amdgcn_s_setprio(1);                                          \
    _Pragma("unroll") for (int m = 0; m < 4; ++m)                           \
      _Pragma("unroll") for (int n = 0; n < NB; ++n)                        \
        acc[(MH)*4 + m][n] = mfma16(af[m], bf[n], acc[(MH)*4 + m][n]);      \
    __builtin_amdgcn_s_setprio(0);                                          \
  }

  // prologue
  STAGE_HALF(Ag, As[0], 0, 2);
  STAGE_HALF(Bg, Bs[0], 0, NB / 2);
  STAGE_HALF(Ag, As[0], 1, 2);
  STAGE_HALF(Bg, Bs[0], 1, NB / 2);
  VMC_CHECK();
  barx();

  const int NT = K >> 6;
  for (int t = 0; t < NT; ++t) {
    const int cur = t & 1;
    const bool pf = (t + 1 < NT);
    const unsigned short* An = Ag + (size_t)(t + 1) * 64;
    const unsigned short* Bn = Bg + (size_t)(t + 1) * 64;
    unsigned short* Ad = As[cur ^ 1];
    unsigned short* Bd = Bs[cur ^ 1];

    PH_READ_A(0, 0); PH_READ_B(0);
    if (pf) STAGE_HALF(An, Ad, 0, 2);
    barx(); PH_MFMA(0); barx();

    PH_READ_A(1, 0);
    if (pf) {
      STAGE_HALF(Bn, Bd, 0, NB / 2);
      VMC_CHECK();
    } else {
      asm volatile("s_waitcnt vmcnt(0)" ::: "memory");
    }
    barx(); PH_MFMA(1); barx();

    PH_READ_A(0, 1); PH_READ_B(1);
    if (pf) STAGE_HALF(An, Ad, 1, 2);
    barx(); PH_MFMA(0); barx();

    PH_READ_A(1, 1);
    if (pf) {
      STAGE_HALF(Bn, Bd, 1, NB / 2);
      VMC_CHECK();
    }
    barx(); PH_MFMA(1); barx();
  }

#pragma unroll
  for (int m8 = 0; m8 < 8; ++m8) {
#pragma unroll
    for (int n = 0; n < NB; ++n) {
      const size_t col = (size_t)bx * (64 * NB) + wn * (16 * NB) + n * 16 + lr;
      float bv = 0.0f;
      if constexpr (HAS_BIAS) bv = bias[col];
#pragma unroll
      for (int r = 0; r < 4; ++r) {
        const size_t row = (size_t)by * 256 + wm * 128 + m8 * 16 + lh * 4 + r;
        const float val = acc[m8][n][r] + bv;
        if constexpr (sizeof(OutT) == 2)
          ((unsigned short*)C)[row * N + col] = f32_bf16(val);
        else
          ((float*)C)[row * N + col] = val;
      }
    }
  }
#undef STAGE_HALF
#undef VMC_CHECK
#undef PH_READ_A
#undef PH_READ_B
#undef PH_MFMA
}

// ---------------- in-register online softmax step (swapped layout) ----------------
static __device__ __forceinline__ void softmax_step(
    const f32x4 st[4], u16x4 pr[4], float& m_run, float& l_run,
    f32x4* oaccq, bool maskT, int kv0, int qglob, int lh) {
  float p[4][4];
#pragma unroll
  for (int n = 0; n < 4; ++n)
#pragma unroll
    for (int r = 0; r < 4; ++r) {
      float val = st[n][r];
      if (maskT && (kv0 + n * 16 + lh * 4 + r > qglob)) val = -1e30f;
      p[n][r] = val;
    }
  float pm[4];
#pragma unroll
  for (int n = 0; n < 4; ++n)
    pm[n] = fmaxf(fmaxf(p[n][0], p[n][1]), fmaxf(p[n][2], p[n][3]));
  float pmax = fmaxf(fmaxf(pm[0], pm[1]), fmaxf(pm[2], pm[3]));
  pmax = fmaxf(pmax, __shfl_xor(pmax, 16));
  pmax = fmaxf(pmax, __shfl_xor(pmax, 32));
  const bool resc = __any(pmax > m_run + 8.0f);
  float alpha = 1.0f;
  if (resc) {
    const float mnew = fmaxf(m_run, pmax);
    alpha = exp2f(m_run - mnew);
    m_run = mnew;
  }
  float rsum = 0.0f;
#pragma unroll
  for (int n = 0; n < 4; ++n) {
#pragma unroll
    for (int r = 0; r < 4; ++r) {
      p[n][r] = exp2f(p[n][r] - m_run);
      rsum += p[n][r];
    }
    // packed bf16 convert (compiler emits v_cvt_pk_bf16_f32)
    __hip_bfloat162 t0 = __float22bfloat162_rn(make_float2(p[n][0], p[n][1]));
    __hip_bfloat162 t1 = __float22bfloat162_rn(make_float2(p[n][2], p[n][3]));
    unsigned lo, hi;
    __builtin_memcpy(&lo, &t0, 4);
    __builtin_memcpy(&hi, &t1, 4);
    unsigned long long both = (unsigned long long)lo | ((unsigned long long)hi << 32);
    u16x4 pk;
    __builtin_memcpy(&pk, &both, 8);
    pr[n] = pk;
  }
  rsum += __shfl_xor(rsum, 16);
  rsum += __shfl_xor(rsum, 32);
  if (resc) {
    l_run = l_run * alpha + rsum;
#pragma unroll
    for (int r = 0; r < 4; ++r) {
      const float a = __shfl(alpha, lh * 4 + r);
#pragma unroll
      for (int nd = 0; nd < 8; ++nd) oaccq[nd][r] *= a;
    }
  } else {
    l_run += rsum;
  }
}

// ---------------- causal GQA flash attention (swapped QK^T, in-reg P) ----------------
// Proven 181us structure: single-buffer K/V (32KB LDS), 2 barriers/tile.
__global__ __launch_bounds__(256, 2) void attn_kernel(
    const unsigned short* __restrict__ qkv, unsigned short* __restrict__ ctx) {
  const int lin = blockIdx.x;
  const int xcd = lin & 7;
  const int j = lin >> 3;
  const int sel = j & 1;
  const int i = j >> 1;
  const int p = i & 3;
  const int qt = 15 - (i >> 2);
  const int s = xcd * 2 + sel;
  const int b = s >> 2, g = s & 3;
  const int h = g * 4 + p;
  const int tid = threadIdx.x;
  const int wave = tid >> 6, lane = tid & 63;
  const int lr = lane & 15, lh = lane >> 4;
  const int qb = qt * 128;
  const int qrow0 = qb + wave * 16;
  const int qrow1 = qb + 64 + wave * 16;

  __shared__ unsigned short Ks[64 * 128];
  __shared__ unsigned short Vts[128 * 64];

  const int vr0 = (tid & 31) * 2;
  const int vc0 = (tid >> 5) * 16;
  const int vcu = vr0 >> 3, vcw = vr0 & 7;

  const unsigned short* qrow_base = qkv + (size_t)b * T_SEQ * QKV_LD;
  const unsigned short* kbase = qrow_base + D_MODEL + g * HDIM;
  const unsigned short* vbase = qrow_base + D_MODEL + KV_DIM + g * HDIM;

  const float QS = 0.1275174f;  // (1/sqrt(128)) * log2(e)
  bf16x8 aq[2][4];
  {
    const unsigned short* qp0 = qrow_base + (size_t)(qrow0 + lr) * QKV_LD + h * HDIM + lh * 8;
    const unsigned short* qp1 = qrow_base + (size_t)(qrow1 + lr) * QKV_LD + h * HDIM + lh * 8;
#pragma unroll
    for (int kk = 0; kk < 4; ++kk) {
      u16x8 r0 = *(const u16x8*)(qp0 + kk * 32);
      u16x8 r1 = *(const u16x8*)(qp1 + kk * 32);
      u16x8 o0, o1;
#pragma unroll
      for (int jj = 0; jj < 8; ++jj) {
        o0[jj] = f32_bf16(__uint_as_float((unsigned)r0[jj] << 16) * QS);
        o1[jj] = f32_bf16(__uint_as_float((unsigned)r1[jj] << 16) * QS);
      }
      aq[0][kk] = __builtin_bit_cast(bf16x8, o0);
      aq[1][kk] = __builtin_bit_cast(bf16x8, o1);
    }
  }

  f32x4 oacc[2][8] = {};
  float m_run0 = -1e30f, l_run0 = 0.0f, m_run1 = -1e30f, l_run1 = 0.0f;

  const int nt = 2 * qt + 2;

  for (int t = 0; t < nt; ++t) {
    const int kv0 = t * 64;
    __syncthreads();
#pragma unroll
    for (int is = 0; is < 4; ++is) {
      const int c = is * 4 + wave;
      const int u = c * 64 + lane;
      const int vu = u ^ ((u >> 4) & 7);
      const int r = vu >> 4;
      const int cc = (vu & 15) * 8;
      gload_lds16(kbase + (size_t)(kv0 + r) * QKV_LD + cc, (char*)Ks + c * 1024);
    }
    {
      const unsigned short* vp = vbase + (size_t)(kv0 + vr0) * QKV_LD + vc0;
      u16x8 va0 = *(const u16x8*)(vp);
      u16x8 va1 = *(const u16x8*)(vp + 8);
      u16x8 vb0 = *(const u16x8*)(vp + QKV_LD);
      u16x8 vb1 = *(const u16x8*)(vp + QKV_LD + 8);
#pragma unroll
      for (int jj = 0; jj < 8; ++jj) {
        const int d0 = vc0 + jj, d1 = vc0 + 8 + jj;
        *(unsigned int*)&Vts[VIDX(d0, vcu) + vcw] =
            (unsigned int)va0[jj] | ((unsigned int)vb0[jj] << 16);
        *(unsigned int*)&Vts[VIDX(d1, vcu) + vcw] =
            (unsigned int)va1[jj] | ((unsigned int)vb1[jj] << 16);
      }
    }
    __syncthreads();

    const bool live0 = (t < nt - 1);
    const bool mask0 = (t == nt - 2);
    const bool mask1 = (t == nt - 1);

    f32x4 st0[4] = {}, st1[4] = {};
    __builtin_amdgcn_s_setprio(1);
#pragma unroll
    for (int n = 0; n < 4; ++n) {
      const int rr = n * 16 + lr;
#pragma unroll
      for (int kk = 0; kk < 4; ++kk) {
        const int lu = rr * 16 + kk * 4 + lh;
        const int pu = lu ^ (rr & 7);
        const bf16x8 ak = *(const bf16x8*)((const char*)Ks + pu * 16);
        if (live0) st0[n] = mfma16(ak, aq[0][kk], st0[n]);
        st1[n] = mfma16(ak, aq[1][kk], st1[n]);
      }
    }
    __builtin_amdgcn_s_setprio(0);

    u16x4 pr0[4], pr1[4];
    if (live0)
      softmax_step(st0, pr0, m_run0, l_run0, oacc[0], mask0, kv0, qrow0 + lr, lh);
    softmax_step(st1, pr1, m_run1, l_run1, oacc[1], mask1, kv0, qrow1 + lr, lh);

    __builtin_amdgcn_s_setprio(1);
#pragma unroll
    for (int n = 0; n < 4; ++n) {
      const int cb = n * 2 + (lh >> 1);
      const int off = (lh & 1) * 4;
#pragma unroll
      for (int nd = 0; nd < 8; ++nd) {
        const int d = nd * 16 + lr;
        const u16x4 vf = *(const u16x4*)&Vts[VIDX(d, cb) + off];
        if (live0) oacc[0][nd] = mfma16x16(pr0[n], vf, oacc[0][nd]);
        oacc[1][nd] = mfma16x16(pr1[n], vf, oacc[1][nd]);
      }
    }
    __builtin_amdgcn_s_setprio(0);
  }

#pragma unroll
  for (int m = 0; m < 2; ++m) {
    const float lm = (m == 0) ? l_run0 : l_run1;
    const int qrow = (m == 0) ? qrow0 : qrow1;
    unsigned short* cp = ctx + ((size_t)b * T_SEQ + qrow) * D_MODEL + h * HDIM;
#pragma unroll
    for (int r = 0; r < 4; ++r) {
      const float inv = 1.0f / __shfl(lm, lh * 4 + r);
#pragma unroll
      for (int nd = 0; nd < 8; ++nd)
        cp[(size_t)(lh * 4 + r) * D_MODEL + nd * 16 + lr] =
            f32_bf16(oacc[m][nd][r] * inv);
    }
  }
}

// ---------------- launch ----------------
extern "C" void kernel_launch(void* const* d_in, const int* in_sizes, int n_in,
                              void* d_out, int out_size, void* d_ws, size_t ws_size,
                              hipStream_t stream) {
  const float* x = (const float*)d_in[0];
  const float* Wq = (const float*)d_in[1];
  const float* Wk = (const float*)d_in[2];
  const float* Wv = (const float*)d_in[3];
  const float* Wo = (const float*)d_in[4];
  const float* bo = (const float*)d_in[5];
  float* out = (float*)d_out;

  char* ws = (char*)d_ws;
  unsigned short* xb = (unsigned short*)(ws + 0);            // 8192x2048 (32MB)
  unsigned short* ctx = (unsigned short*)(ws + 0);           // alias (attn after QKV GEMM)
  unsigned short* qkv = (unsigned short*)(ws + 33554432);    // 8192x3072 (48MB)
  unsigned short* WqkvT = (unsigned short*)(ws + 83886080);  // 3072x2048 (12MB)
  unsigned short* WoT = (unsigned short*)(ws + 96468992);    // 2048x2048 (8MB)

  // fused prep: cvt (16384 blocks) + 4x transpose (10240 blocks)
  prep_kernel<<<CVT_BLOCKS + 10240, 256, 0, stream>>>(x, Wq, Wk, Wv, Wo, xb, WqkvT, WoT);

  // fused QKV projection: [8192,2048] @ [2048,3072] -> [8192,3072]  (NB=4, proven)
  gemm256_kernel<unsigned short, false, 4><<<dim3(QKV_LD / 256, MT / 256), 512, 0, stream>>>(
      xb, WqkvT, qkv, nullptr, MT, QKV_LD, D_MODEL);

  attn_kernel<<<1024, 256, 0, stream>>>(qkv, ctx);

  // O-projection: NB=4 (BN=256), grid 8x32 = 256 = 1 exact round (proven)
  gemm256_kernel<float, true, 4><<<dim3(D_MODEL / 256, MT / 256), 512, 0, stream>>>(
      ctx, WoT, out, bo, MT, D_MODEL, D_MODEL);
}

// Round 20
// 384.075 us; speedup vs baseline: 1.0228x; 1.0228x over previous
//
#include <hip/hip_runtime.h>
#include <hip/hip_bf16.h>
#include <stdint.h>
#include <math.h>

#define T_SEQ 2048
#define D_MODEL 2048
#define KV_DIM 512
#define QKV_LD 3072  // fused q|k|v row stride
#define NHEADS 16
#define HDIM 128
#define BATCH 4
#define MT (BATCH * T_SEQ)  // 8192 rows

typedef __attribute__((ext_vector_type(4))) float f32x4;
typedef __attribute__((ext_vector_type(8))) __bf16 bf16x8;
typedef __attribute__((ext_vector_type(4))) __bf16 bf16x4;
typedef __attribute__((ext_vector_type(8))) unsigned short u16x8;
typedef __attribute__((ext_vector_type(4))) unsigned short u16x4;
typedef __attribute__((ext_vector_type(4))) short s16x4;

static __device__ __forceinline__ unsigned short f32_bf16(float f) {
  unsigned u = __float_as_uint(f);
  u += 0x7fff + ((u >> 16) & 1);  // RNE
  return (unsigned short)(u >> 16);
}

static __device__ __forceinline__ void gload_lds16(const void* g, void* l) {
  __builtin_amdgcn_global_load_lds(
      (__attribute__((address_space(1))) void*)(const_cast<void*>(g)),
      (__attribute__((address_space(3))) void*)l, 16, 0, 0);
}

static __device__ __forceinline__ f32x4 mfma16(bf16x8 a, bf16x8 b, f32x4 c) {
  return __builtin_amdgcn_mfma_f32_16x16x32_bf16(a, b, c, 0, 0, 0);
}

// K=16 bf16 MFMA: A/B = 4 bf16 (k = (lane>>4)*4+j), C/D layout same as 16x16x32.
static __device__ __forceinline__ f32x4 mfma16x16(u16x4 a, u16x4 b, f32x4 c) {
#if __has_builtin(__builtin_amdgcn_mfma_f32_16x16x16bf16_1k)
  return __builtin_amdgcn_mfma_f32_16x16x16bf16_1k(
      __builtin_bit_cast(s16x4, a), __builtin_bit_cast(s16x4, b), c, 0, 0, 0);
#elif __has_builtin(__builtin_amdgcn_mfma_f32_16x16x16_bf16)
  return __builtin_amdgcn_mfma_f32_16x16x16_bf16(
      __builtin_bit_cast(bf16x4, a), __builtin_bit_cast(bf16x4, b), c, 0, 0, 0);
#else
  f32x4 d;
  asm("v_mfma_f32_16x16x16_bf16 %0, %1, %2, %3" : "=v"(d) : "v"(a), "v"(b), "v"(c));
  return d;
#endif
}

static __device__ __forceinline__ void barx() {
  asm volatile("" ::: "memory");
  __builtin_amdgcn_s_barrier();
  asm volatile("" ::: "memory");
}

// swizzled [rows][8 units of 16B] u16-index helper (unit ^= row&7) — attn V layout
#define VIDX(d, c) (((((d) << 3) + ((c) ^ ((d) & 7))) << 3))

// ---------------- f32 -> bf16 convert (vectorized) ----------------
__global__ void cvt_kernel(const float* __restrict__ in, unsigned short* __restrict__ out, int n4) {
  int i = blockIdx.x * 256 + threadIdx.x;
  if (i >= n4) return;
  f32x4 v = ((const f32x4*)in)[i];
  u16x4 o;
#pragma unroll
  for (int j = 0; j < 4; ++j) o[j] = f32_bf16(v[j]);
  ((u16x4*)out)[i] = o;
}

// ---------------- fused 4x transpose: W[K][N] f32 -> Wt[N][K] bf16 ----------------
__global__ void transpose4_kernel(const float* __restrict__ Wq, const float* __restrict__ Wk,
                                  const float* __restrict__ Wv, const float* __restrict__ Wo,
                                  unsigned short* __restrict__ WqkvT,
                                  unsigned short* __restrict__ WoT) {
  const int bid = blockIdx.x;
  const float* W;
  unsigned short* Wt;
  int N, bx, by;
  if (bid < 4096) {
    W = Wq; Wt = WqkvT; N = 2048; bx = bid & 63; by = bid >> 6;
  } else if (bid < 5120) {
    const int r = bid - 4096;
    W = Wk; Wt = WqkvT + (size_t)2048 * 2048; N = 512; bx = r & 15; by = r >> 4;
  } else if (bid < 6144) {
    const int r = bid - 5120;
    W = Wv; Wt = WqkvT + (size_t)2560 * 2048; N = 512; bx = r & 15; by = r >> 4;
  } else {
    const int r = bid - 6144;
    W = Wo; Wt = WoT; N = 2048; bx = r & 63; by = r >> 6;
  }
  const int K = 2048;
  __shared__ float tile[32][33];
  const int x0 = bx * 32, y0 = by * 32;
  const int tx = threadIdx.x, ty = threadIdx.y;
#pragma unroll
  for (int i = 0; i < 32; i += 8)
    tile[ty + i][tx] = W[(size_t)(y0 + ty + i) * N + x0 + tx];
  __syncthreads();
#pragma unroll
  for (int i = 0; i < 32; i += 8)
    Wt[(size_t)(x0 + ty + i) * K + y0 + tx] = f32_bf16(tile[tx][ty + i]);
}

// ---------------- 256xBN x64 8-phase GEMM: C[M,N] = A[M,K] @ Bt[N,K]^T ----------------
// NB=4 -> BN=256, LDS 128KB (proven best; NB=2 regressed — A-staging doubles, R17).
// LDS subtile = 16 rows x 32 u16 (1KB); 16B-unit swizzle phys = logical ^ ((row>>1)&3)
// on both staging source col and fragment read (rule #21 involution).
template <typename OutT, bool HAS_BIAS, int NB>
__global__ __launch_bounds__(512, 2) void gemm256_kernel(
    const unsigned short* __restrict__ A, const unsigned short* __restrict__ Bt,
    OutT* __restrict__ C, const float* __restrict__ bias, int M, int N, int K) {
  __shared__ unsigned short As[2][16384];
  __shared__ unsigned short Bs[2][4096 * NB];
  const int tid = threadIdx.x;
  const int wave = tid >> 6, lane = tid & 63;
  const int lr = lane & 15, lh = lane >> 4;
  const int wm = wave >> 2, wn = wave & 3;  // 2M x 4N waves

  // bijective XCD swizzle (nwg % 8 == 0 for our grids)
  const int gx = gridDim.x;
  const int nwg = gx * gridDim.y;
  int flat = blockIdx.y * gx + blockIdx.x;
  flat = (flat & 7) * (nwg >> 3) + (flat >> 3);
  const int bx = flat % gx, by = flat / gx;

  const unsigned short* Ag = A + (size_t)by * 256 * K;
  const unsigned short* Bg = Bt + (size_t)bx * (64 * NB) * K;

  // staging geometry: thread stages 16B unit (lane&3) of subtile row (lane>>2)
  const int srow_lo = lane >> 2;
  const int scol = ((lane & 3) ^ ((srow_lo >> 1) & 3)) * 8;  // inverse-swizzled source col (u16)

#define STAGE_HALF(SRC, DST, HK, NS)                                          \
  {                                                                           \
    _Pragma("unroll") for (int s = 0; s < (NS); ++s) {                        \
      const int jj = s * 8 + wave;                                            \
      gload_lds16((SRC) + (size_t)(jj * 16 + srow_lo) * K + (HK) * 32 + scol, \
                  (char*)(DST) + (jj * 2 + (HK)) * 1024);                     \
    }                                                                         \
  }
#define VMC_CHECK()                                                           \
  {                                                                           \
    if constexpr (NB == 4) asm volatile("s_waitcnt vmcnt(4)" ::: "memory");   \
    else asm volatile("s_waitcnt vmcnt(3)" ::: "memory");                     \
  }

  // fragment read offsets (u16): row lr, logical 16B-unit lh -> phys lh^((lr>>1)&3)
  const int aoff = lr * 32 + ((lh ^ ((lr >> 1) & 3)) * 8);
  const int abase = wm * 8 * 1024;
  const int bbase = wn * NB * 1024;

  f32x4 acc[8][NB] = {};
  bf16x8 af[4], bf[NB];

#define PH_READ_A(MH, KS)                                                   \
  {                                                                         \
    _Pragma("unroll") for (int m = 0; m < 4; ++m)                           \
      af[m] = *(const bf16x8*)&As[cur][abase + ((MH)*4 + m) * 1024 + (KS)*512 + aoff]; \
  }
#define PH_READ_B(KS)                                                       \
  {                                                                         \
    _Pragma("unroll") for (int n = 0; n < NB; ++n)                          \
      bf[n] = *(const bf16x8*)&Bs[cur][bbase + n * 1024 + (KS)*512 + aoff]; \
  }
#define PH_MFMA(MH)                                                         \
  {                                                                         \
    __builtin_amdgcn_s_setprio(1);                                          \
    _Pragma("unroll") for (int m = 0; m < 4; ++m)                           \
      _Pragma("unroll") for (int n = 0; n < NB; ++n)                        \
        acc[(MH)*4 + m][n] = mfma16(af[m], bf[n], acc[(MH)*4 + m][n]);      \
    __builtin_amdgcn_s_setprio(0);                                          \
  }

  // prologue
  STAGE_HALF(Ag, As[0], 0, 2);
  STAGE_HALF(Bg, Bs[0], 0, NB / 2);
  STAGE_HALF(Ag, As[0], 1, 2);
  STAGE_HALF(Bg, Bs[0], 1, NB / 2);
  VMC_CHECK();
  barx();

  const int NT = K >> 6;
  for (int t = 0; t < NT; ++t) {
    const int cur = t & 1;
    const bool pf = (t + 1 < NT);
    const unsigned short* An = Ag + (size_t)(t + 1) * 64;
    const unsigned short* Bn = Bg + (size_t)(t + 1) * 64;
    unsigned short* Ad = As[cur ^ 1];
    unsigned short* Bd = Bs[cur ^ 1];

    PH_READ_A(0, 0); PH_READ_B(0);
    if (pf) STAGE_HALF(An, Ad, 0, 2);
    barx(); PH_MFMA(0); barx();

    PH_READ_A(1, 0);
    if (pf) {
      STAGE_HALF(Bn, Bd, 0, NB / 2);
      VMC_CHECK();
    } else {
      asm volatile("s_waitcnt vmcnt(0)" ::: "memory");
    }
    barx(); PH_MFMA(1); barx();

    PH_READ_A(0, 1); PH_READ_B(1);
    if (pf) STAGE_HALF(An, Ad, 1, 2);
    barx(); PH_MFMA(0); barx();

    PH_READ_A(1, 1);
    if (pf) {
      STAGE_HALF(Bn, Bd, 1, NB / 2);
      VMC_CHECK();
    }
    barx(); PH_MFMA(1); barx();
  }

#pragma unroll
  for (int m8 = 0; m8 < 8; ++m8) {
#pragma unroll
    for (int n = 0; n < NB; ++n) {
      const size_t col = (size_t)bx * (64 * NB) + wn * (16 * NB) + n * 16 + lr;
      float bv = 0.0f;
      if constexpr (HAS_BIAS) bv = bias[col];
#pragma unroll
      for (int r = 0; r < 4; ++r) {
        const size_t row = (size_t)by * 256 + wm * 128 + m8 * 16 + lh * 4 + r;
        const float val = acc[m8][n][r] + bv;
        if constexpr (sizeof(OutT) == 2)
          ((unsigned short*)C)[row * N + col] = f32_bf16(val);
        else
          ((float*)C)[row * N + col] = val;
      }
    }
  }
#undef STAGE_HALF
#undef VMC_CHECK
#undef PH_READ_A
#undef PH_READ_B
#undef PH_MFMA
}

// ---------------- in-register online softmax step (swapped layout) ----------------
static __device__ __forceinline__ void softmax_step(
    const f32x4 st[4], u16x4 pr[4], float& m_run, float& l_run,
    f32x4* oaccq, bool maskT, int kv0, int qglob, int lh) {
  float p[4][4];
#pragma unroll
  for (int n = 0; n < 4; ++n)
#pragma unroll
    for (int r = 0; r < 4; ++r) {
      float val = st[n][r];
      if (maskT && (kv0 + n * 16 + lh * 4 + r > qglob)) val = -1e30f;
      p[n][r] = val;
    }
  float pm[4];
#pragma unroll
  for (int n = 0; n < 4; ++n)
    pm[n] = fmaxf(fmaxf(p[n][0], p[n][1]), fmaxf(p[n][2], p[n][3]));
  float pmax = fmaxf(fmaxf(pm[0], pm[1]), fmaxf(pm[2], pm[3]));
  pmax = fmaxf(pmax, __shfl_xor(pmax, 16));
  pmax = fmaxf(pmax, __shfl_xor(pmax, 32));
  const bool resc = __any(pmax > m_run + 8.0f);
  float alpha = 1.0f;
  if (resc) {
    const float mnew = fmaxf(m_run, pmax);
    alpha = exp2f(m_run - mnew);
    m_run = mnew;
  }
  float rsum = 0.0f;
#pragma unroll
  for (int n = 0; n < 4; ++n) {
#pragma unroll
    for (int r = 0; r < 4; ++r) {
      p[n][r] = exp2f(p[n][r] - m_run);
      rsum += p[n][r];
    }
    // packed bf16 convert (compiler emits v_cvt_pk_bf16_f32)
    __hip_bfloat162 t0 = __float22bfloat162_rn(make_float2(p[n][0], p[n][1]));
    __hip_bfloat162 t1 = __float22bfloat162_rn(make_float2(p[n][2], p[n][3]));
    unsigned lo, hi;
    __builtin_memcpy(&lo, &t0, 4);
    __builtin_memcpy(&hi, &t1, 4);
    unsigned long long both = (unsigned long long)lo | ((unsigned long long)hi << 32);
    u16x4 pk;
    __builtin_memcpy(&pk, &both, 8);
    pr[n] = pk;
  }
  rsum += __shfl_xor(rsum, 16);
  rsum += __shfl_xor(rsum, 32);
  if (resc) {
    l_run = l_run * alpha + rsum;
#pragma unroll
    for (int r = 0; r < 4; ++r) {
      const float a = __shfl(alpha, lh * 4 + r);
#pragma unroll
      for (int nd = 0; nd < 8; ++nd) oaccq[nd][r] *= a;
    }
  } else {
    l_run += rsum;
  }
}

// ---------------- causal GQA flash attention (swapped QK^T, in-reg P) ----------------
// Proven 181us structure: single-buffer K/V (32KB LDS), 2 barriers/tile.
__global__ __launch_bounds__(256, 2) void attn_kernel(
    const unsigned short* __restrict__ qkv, unsigned short* __restrict__ ctx) {
  const int lin = blockIdx.x;
  const int xcd = lin & 7;
  const int j = lin >> 3;
  const int sel = j & 1;
  const int i = j >> 1;
  const int p = i & 3;
  const int qt = 15 - (i >> 2);
  const int s = xcd * 2 + sel;
  const int b = s >> 2, g = s & 3;
  const int h = g * 4 + p;
  const int tid = threadIdx.x;
  const int wave = tid >> 6, lane = tid & 63;
  const int lr = lane & 15, lh = lane >> 4;
  const int qb = qt * 128;
  const int qrow0 = qb + wave * 16;
  const int qrow1 = qb + 64 + wave * 16;

  __shared__ unsigned short Ks[64 * 128];
  __shared__ unsigned short Vts[128 * 64];

  const int vr0 = (tid & 31) * 2;
  const int vc0 = (tid >> 5) * 16;
  const int vcu = vr0 >> 3, vcw = vr0 & 7;

  const unsigned short* qrow_base = qkv + (size_t)b * T_SEQ * QKV_LD;
  const unsigned short* kbase = qrow_base + D_MODEL + g * HDIM;
  const unsigned short* vbase = qrow_base + D_MODEL + KV_DIM + g * HDIM;

  const float QS = 0.1275174f;  // (1/sqrt(128)) * log2(e)
  bf16x8 aq[2][4];
  {
    const unsigned short* qp0 = qrow_base + (size_t)(qrow0 + lr) * QKV_LD + h * HDIM + lh * 8;
    const unsigned short* qp1 = qrow_base + (size_t)(qrow1 + lr) * QKV_LD + h * HDIM + lh * 8;
#pragma unroll
    for (int kk = 0; kk < 4; ++kk) {
      u16x8 r0 = *(const u16x8*)(qp0 + kk * 32);
      u16x8 r1 = *(const u16x8*)(qp1 + kk * 32);
      u16x8 o0, o1;
#pragma unroll
      for (int jj = 0; jj < 8; ++jj) {
        o0[jj] = f32_bf16(__uint_as_float((unsigned)r0[jj] << 16) * QS);
        o1[jj] = f32_bf16(__uint_as_float((unsigned)r1[jj] << 16) * QS);
      }
      aq[0][kk] = __builtin_bit_cast(bf16x8, o0);
      aq[1][kk] = __builtin_bit_cast(bf16x8, o1);
    }
  }

  f32x4 oacc[2][8] = {};
  float m_run0 = -1e30f, l_run0 = 0.0f, m_run1 = -1e30f, l_run1 = 0.0f;

  const int nt = 2 * qt + 2;

  for (int t = 0; t < nt; ++t) {
    const int kv0 = t * 64;
    __syncthreads();
#pragma unroll
    for (int is = 0; is < 4; ++is) {
      const int c = is * 4 + wave;
      const int u = c * 64 + lane;
      const int vu = u ^ ((u >> 4) & 7);
      const int r = vu >> 4;
      const int cc = (vu & 15) * 8;
      gload_lds16(kbase + (size_t)(kv0 + r) * QKV_LD + cc, (char*)Ks + c * 1024);
    }
    {
      const unsigned short* vp = vbase + (size_t)(kv0 + vr0) * QKV_LD + vc0;
      u16x8 va0 = *(const u16x8*)(vp);
      u16x8 va1 = *(const u16x8*)(vp + 8);
      u16x8 vb0 = *(const u16x8*)(vp + QKV_LD);
      u16x8 vb1 = *(const u16x8*)(vp + QKV_LD + 8);
#pragma unroll
      for (int jj = 0; jj < 8; ++jj) {
        const int d0 = vc0 + jj, d1 = vc0 + 8 + jj;
        *(unsigned int*)&Vts[VIDX(d0, vcu) + vcw] =
            (unsigned int)va0[jj] | ((unsigned int)vb0[jj] << 16);
        *(unsigned int*)&Vts[VIDX(d1, vcu) + vcw] =
            (unsigned int)va1[jj] | ((unsigned int)vb1[jj] << 16);
      }
    }
    __syncthreads();

    const bool live0 = (t < nt - 1);
    const bool mask0 = (t == nt - 2);
    const bool mask1 = (t == nt - 1);

    f32x4 st0[4] = {}, st1[4] = {};
    __builtin_amdgcn_s_setprio(1);
#pragma unroll
    for (int n = 0; n < 4; ++n) {
      const int rr = n * 16 + lr;
#pragma unroll
      for (int kk = 0; kk < 4; ++kk) {
        const int lu = rr * 16 + kk * 4 + lh;
        const int pu = lu ^ (rr & 7);
        const bf16x8 ak = *(const bf16x8*)((const char*)Ks + pu * 16);
        if (live0) st0[n] = mfma16(ak, aq[0][kk], st0[n]);
        st1[n] = mfma16(ak, aq[1][kk], st1[n]);
      }
    }
    __builtin_amdgcn_s_setprio(0);

    u16x4 pr0[4], pr1[4];
    if (live0)
      softmax_step(st0, pr0, m_run0, l_run0, oacc[0], mask0, kv0, qrow0 + lr, lh);
    softmax_step(st1, pr1, m_run1, l_run1, oacc[1], mask1, kv0, qrow1 + lr, lh);

    __builtin_amdgcn_s_setprio(1);
#pragma unroll
    for (int n = 0; n < 4; ++n) {
      const int cb = n * 2 + (lh >> 1);
      const int off = (lh & 1) * 4;
#pragma unroll
      for (int nd = 0; nd < 8; ++nd) {
        const int d = nd * 16 + lr;
        const u16x4 vf = *(const u16x4*)&Vts[VIDX(d, cb) + off];
        if (live0) oacc[0][nd] = mfma16x16(pr0[n], vf, oacc[0][nd]);
        oacc[1][nd] = mfma16x16(pr1[n], vf, oacc[1][nd]);
      }
    }
    __builtin_amdgcn_s_setprio(0);
  }

#pragma unroll
  for (int m = 0; m < 2; ++m) {
    const float lm = (m == 0) ? l_run0 : l_run1;
    const int qrow = (m == 0) ? qrow0 : qrow1;
    unsigned short* cp = ctx + ((size_t)b * T_SEQ + qrow) * D_MODEL + h * HDIM;
#pragma unroll
    for (int r = 0; r < 4; ++r) {
      const float inv = 1.0f / __shfl(lm, lh * 4 + r);
#pragma unroll
      for (int nd = 0; nd < 8; ++nd)
        cp[(size_t)(lh * 4 + r) * D_MODEL + nd * 16 + lr] =
            f32_bf16(oacc[m][nd][r] * inv);
    }
  }
}

// ---------------- launch ----------------
extern "C" void kernel_launch(void* const* d_in, const int* in_sizes, int n_in,
                              void* d_out, int out_size, void* d_ws, size_t ws_size,
                              hipStream_t stream) {
  const float* x = (const float*)d_in[0];
  const float* Wq = (const float*)d_in[1];
  const float* Wk = (const float*)d_in[2];
  const float* Wv = (const float*)d_in[3];
  const float* Wo = (const float*)d_in[4];
  const float* bo = (const float*)d_in[5];
  float* out = (float*)d_out;

  char* ws = (char*)d_ws;
  unsigned short* xb = (unsigned short*)(ws + 0);            // 8192x2048 (32MB)
  unsigned short* ctx = (unsigned short*)(ws + 0);           // alias (attn after QKV GEMM)
  unsigned short* qkv = (unsigned short*)(ws + 33554432);    // 8192x3072 (48MB)
  unsigned short* WqkvT = (unsigned short*)(ws + 83886080);  // 3072x2048 (12MB)
  unsigned short* WoT = (unsigned short*)(ws + 96468992);    // 2048x2048 (8MB)

  const int n4 = MT * D_MODEL / 4;
  cvt_kernel<<<(n4 + 255) / 256, 256, 0, stream>>>(x, xb, n4);
  transpose4_kernel<<<10240, dim3(32, 8), 0, stream>>>(Wq, Wk, Wv, Wo, WqkvT, WoT);

  // fused QKV projection: [8192,2048] @ [2048,3072] -> [8192,3072]  (NB=4, proven)
  gemm256_kernel<unsigned short, false, 4><<<dim3(QKV_LD / 256, MT / 256), 512, 0, stream>>>(
      xb, WqkvT, qkv, nullptr, MT, QKV_LD, D_MODEL);

  attn_kernel<<<1024, 256, 0, stream>>>(qkv, ctx);

  // O-projection: NB=4 (BN=256), grid 8x32 = 256 = 1 exact round (proven)
  gemm256_kernel<float, true, 4><<<dim3(D_MODEL / 256, MT / 256), 512, 0, stream>>>(
      ctx, WoT, out, bo, MT, D_MODEL, D_MODEL);
}